// Round 1
// baseline (3633.401 us; speedup 1.0000x reference)
//
#include <hip/hip_runtime.h>
#include <hip/hip_bf16.h>
#include <math.h>

constexpr int NN = 50000;    // nodes
constexpr int NE = 600000;   // edges
constexpr int HD = 128;      // hidden
constexpr int NG = 512;      // graphs
constexpr float EPSV = 1e-5f;
constexpr float PI_F = 3.14159265358979323846f;

static __device__ __forceinline__ float wave_reduce(float v) {
#pragma unroll
  for (int off = 32; off > 0; off >>= 1) v += __shfl_xor(v, off, 64);
  return v;
}

// ---------------- CSR build ----------------
__global__ void deg_hist(const int* __restrict__ dst, int* __restrict__ deg) {
  int i = blockIdx.x * 256 + threadIdx.x;
  if (i < NE) atomicAdd(&deg[dst[i]], 1);
}

__global__ void scanA(const int* __restrict__ deg, int* __restrict__ part) {
  __shared__ int sh[256];
  int b = blockIdx.x, tid = threadIdx.x;
  int sum = 0;
  for (int k = tid; k < 1024; k += 256) {
    int idx = b * 1024 + k;
    if (idx < NN) sum += deg[idx];
  }
  sh[tid] = sum; __syncthreads();
  for (int s = 128; s; s >>= 1) { if (tid < s) sh[tid] += sh[tid + s]; __syncthreads(); }
  if (tid == 0) part[b] = sh[0];
}

__global__ void scanB(int* __restrict__ part, int nb) {
  if (threadIdx.x == 0) {
    int run = 0;
    for (int i = 0; i < nb; ++i) { int v = part[i]; part[i] = run; run += v; }
  }
}

__global__ void scanC(const int* __restrict__ deg, const int* __restrict__ part,
                      int* __restrict__ rowstart, int* __restrict__ cursor) {
  __shared__ int sh[256];
  int b = blockIdx.x, tid = threadIdx.x;
  int base = b * 1024 + tid * 4;
  int v[4];
#pragma unroll
  for (int k = 0; k < 4; ++k) v[k] = (base + k < NN) ? deg[base + k] : 0;
  int tot = v[0] + v[1] + v[2] + v[3];
  sh[tid] = tot; __syncthreads();
  for (int off = 1; off < 256; off <<= 1) {
    int x = (tid >= off) ? sh[tid - off] : 0;
    __syncthreads();
    sh[tid] += x;
    __syncthreads();
  }
  int excl = part[b] + sh[tid] - tot;
#pragma unroll
  for (int k = 0; k < 4; ++k) {
    if (base + k < NN) { rowstart[base + k] = excl; cursor[base + k] = excl; excl += v[k]; }
  }
}

__global__ void scatter_k(const int* __restrict__ src, const int* __restrict__ dst,
                          int* __restrict__ cursor, int* __restrict__ ceid, int* __restrict__ csrc) {
  int i = blockIdx.x * 256 + threadIdx.x;
  if (i < NE) {
    int d = dst[i];
    int pos = atomicAdd(&cursor[d], 1);
    ceid[pos] = i;
    csrc[pos] = src[i];
  }
}

// ---------------- self-loop attr (mean of incoming edge_attr) ----------------
__global__ void sloop_k(const float* __restrict__ eattr, const int* __restrict__ rowstart,
                        const int* __restrict__ deg, const int* __restrict__ ceid,
                        float* __restrict__ sloop) {
  int tid = threadIdx.x;
  int j = tid & 127, half = tid >> 7;
  int n = blockIdx.x * 2 + half;
  if (n >= NN) return;
  int st = rowstart[n], cnt = deg[n];
  float a = 0.f;
  for (int k = 0; k < cnt; ++k) {
    int e = ceid[st + k];
    a += eattr[(size_t)e * HD + j];
  }
  sloop[(size_t)n * HD + j] = a / (float)max(cnt, 1);
}

// ---------------- node GEMM: out = act(in @ W + b), optionally dual ----------------
template <int DUAL, int ACT>
__global__ __launch_bounds__(256) void node_gemm(
    const float* __restrict__ in, const float* __restrict__ W1, const float* __restrict__ b1,
    const float* __restrict__ W2, const float* __restrict__ b2,
    float* __restrict__ o1, float* __restrict__ o2) {
  __shared__ float xs[32][HD];
  const int tid = threadIdx.x;
  const int j = tid & 127;
  const int half = tid >> 7;
  const int r0 = blockIdx.x * 32;
  for (int k = tid; k < 32 * HD / 4; k += 256) {
    int r = k >> 5, c4 = k & 31;
    float4 v = make_float4(0.f, 0.f, 0.f, 0.f);
    if (r0 + r < NN) v = ((const float4*)(in + (size_t)(r0 + r) * HD))[c4];
    *((float4*)&xs[r][c4 * 4]) = v;
  }
  __syncthreads();
  float acc1[16], acc2[16];
  const float bb1 = b1[j];
#pragma unroll
  for (int k = 0; k < 16; ++k) acc1[k] = bb1;
  if (DUAL) {
    const float bb2 = b2[j];
#pragma unroll
    for (int k = 0; k < 16; ++k) acc2[k] = bb2;
  }
#pragma unroll 4
  for (int i = 0; i < HD; i += 4) {
    const float w10 = W1[(i + 0) * HD + j], w11 = W1[(i + 1) * HD + j];
    const float w12 = W1[(i + 2) * HD + j], w13 = W1[(i + 3) * HD + j];
    float w20 = 0.f, w21 = 0.f, w22 = 0.f, w23 = 0.f;
    if (DUAL) {
      w20 = W2[(i + 0) * HD + j]; w21 = W2[(i + 1) * HD + j];
      w22 = W2[(i + 2) * HD + j]; w23 = W2[(i + 3) * HD + j];
    }
#pragma unroll
    for (int k = 0; k < 16; ++k) {
      const float4 a = *(const float4*)&xs[half * 16 + k][i];
      acc1[k] = fmaf(a.x, w10, fmaf(a.y, w11, fmaf(a.z, w12, fmaf(a.w, w13, acc1[k]))));
      if (DUAL)
        acc2[k] = fmaf(a.x, w20, fmaf(a.y, w21, fmaf(a.z, w22, fmaf(a.w, w23, acc2[k]))));
    }
  }
#pragma unroll
  for (int k = 0; k < 16; ++k) {
    int r = r0 + half * 16 + k;
    if (r < NN) {
      float v1 = acc1[k];
      if (ACT) v1 = tanhf(v1);
      o1[(size_t)r * HD + j] = v1;
      if (DUAL) o2[(size_t)r * HD + j] = acc2[k];
    }
  }
}

// ---------------- per-edge attention logits: ev[e] = att . leaky(xl[src]+xr[dst]+ea@We) ----------------
__global__ __launch_bounds__(256, 2) void edge_scores(
    const float* __restrict__ eattr, const float* __restrict__ sloop,
    const int* __restrict__ src, const int* __restrict__ dst,
    const float* __restrict__ xl, const float* __restrict__ xr,
    const float* __restrict__ We, const float* __restrict__ att,
    float* __restrict__ ev) {
  __shared__ float We_s[HD * HD];      // 64 KB
  __shared__ float ea_s[16][HD];       // 8 KB
  __shared__ float red_s[2][2][8];
  const int tid = threadIdx.x;
  const int j = tid & 127;
  const int grp = tid >> 7;            // 0/1: which 8-edge group
  const int lane = tid & 63;
  const int wv = (tid >> 6) & 1;       // wave within group
  for (int k = tid; k < HD * HD / 4; k += 256)
    ((float4*)We_s)[k] = ((const float4*)We)[k];
  const float attj = att[j];
  const int total = NE + NN;
  for (int base = blockIdx.x * 16; base < total; base += gridDim.x * 16) {
    // stage 16 edge-attr rows (real edges from eattr, self-loops from sloop)
    for (int k = tid; k < 16 * HD / 4; k += 256) {
      int le = k >> 5, c4 = k & 31;
      int e = base + le;
      float4 v = make_float4(0.f, 0.f, 0.f, 0.f);
      if (e < total) {
        const float* p = (e < NE) ? (eattr + (size_t)e * HD) : (sloop + (size_t)(e - NE) * HD);
        v = ((const float4*)p)[c4];
      }
      *((float4*)&ea_s[le][c4 * 4]) = v;
    }
    __syncthreads();   // A: staging (and first-iter We) visible
    const int e0 = base + grp * 8;
    float xsum[8];
#pragma unroll
    for (int k = 0; k < 8; ++k) {
      int e = e0 + k;
      float v = 0.f;
      if (e < total) {
        int s_, d_;
        if (e < NE) { s_ = src[e]; d_ = dst[e]; } else { s_ = d_ = e - NE; }
        v = xl[(size_t)s_ * HD + j] + xr[(size_t)d_ * HD + j];
      }
      xsum[k] = v;
    }
    float t[8] = {0.f, 0.f, 0.f, 0.f, 0.f, 0.f, 0.f, 0.f};
#pragma unroll 8
    for (int i = 0; i < HD; i += 4) {
      const float w0 = We_s[(i + 0) * HD + j];
      const float w1 = We_s[(i + 1) * HD + j];
      const float w2 = We_s[(i + 2) * HD + j];
      const float w3 = We_s[(i + 3) * HD + j];
#pragma unroll
      for (int k = 0; k < 8; ++k) {
        const float4 a = *(const float4*)&ea_s[grp * 8 + k][i];
        t[k] = fmaf(a.x, w0, fmaf(a.y, w1, fmaf(a.z, w2, fmaf(a.w, w3, t[k]))));
      }
    }
#pragma unroll
    for (int k = 0; k < 8; ++k) {
      float m = xsum[k] + t[k];
      m = m > 0.f ? m : 0.2f * m;
      float p = wave_reduce(m * attj);
      if (lane == 0) red_s[grp][wv][k] = p;
    }
    __syncthreads();   // B: red_s visible; all ea_s reads done
    if (tid < 16) {
      int gg = tid >> 3, kk = tid & 7;
      int e = base + gg * 8 + kk;
      if (e < total) ev[e] = red_s[gg][0][kk] + red_s[gg][1][kk];
    }
  }
}

// ---------------- per-node softmax-aggregate: h[n] = sum alpha_e * xl[src_e] + cb ----------------
__global__ void aggregate(const float* __restrict__ xl, const float* __restrict__ evals,
                          const int* __restrict__ rowstart, const int* __restrict__ deg,
                          const int* __restrict__ ceid, const int* __restrict__ csrc,
                          const float* __restrict__ cb, float* __restrict__ hout) {
  int tid = threadIdx.x;
  int j = tid & 127, half = tid >> 7;
  int n = blockIdx.x * 2 + half;
  if (n >= NN) return;
  int st = rowstart[n], cnt = deg[n];
  // init with self-loop (edge id NE+n, feature row xl[n])
  float m = evals[NE + n];
  float s = 1.f;
  float p = xl[(size_t)n * HD + j];
  for (int k = 0; k < cnt; ++k) {
    int e = ceid[st + k];
    int sc = csrc[st + k];
    float evv = evals[e];
    float x = xl[(size_t)sc * HD + j];
    float nm = fmaxf(m, evv);
    float c = __expf(m - nm);
    float w = __expf(evv - nm);
    s = s * c + w;
    p = p * c + w * x;
    m = nm;
  }
  hout[(size_t)n * HD + j] = p / s + cb[j];
}

// ---------------- batchnorm stats / finalize / apply+tanh ----------------
__global__ void colstats(const float* __restrict__ h, float* __restrict__ cs, float* __restrict__ csq) {
  __shared__ float s1[256], s2[256];
  int tid = threadIdx.x;
  int j = tid & 127, half = tid >> 7;
  int rbeg = blockIdx.x * 256, rend = min(NN, rbeg + 256);
  float a = 0.f, b = 0.f;
  for (int r = rbeg + half; r < rend; r += 2) {
    float v = h[(size_t)r * HD + j];
    a += v; b += v * v;
  }
  s1[tid] = a; s2[tid] = b; __syncthreads();
  if (half == 0) {
    atomicAdd(&cs[j], s1[j] + s1[128 + j]);
    atomicAdd(&csq[j], s2[j] + s2[128 + j]);
  }
}

__global__ void bnfinal(const float* __restrict__ cs, const float* __restrict__ csq,
                        const float* __restrict__ g, const float* __restrict__ be,
                        float* __restrict__ scale, float* __restrict__ shift) {
  int j = threadIdx.x;
  float mu = cs[j] / (float)NN;
  float var = csq[j] / (float)NN - mu * mu;
  float sc = g[j] * rsqrtf(var + EPSV);
  scale[j] = sc;
  shift[j] = be[j] - mu * sc;
}

__global__ void bn_tanh(const float4* __restrict__ h, const float* __restrict__ scale,
                        const float* __restrict__ shift, float4* __restrict__ o) {
  const int n4 = NN * HD / 4;
  for (int i = blockIdx.x * blockDim.x + threadIdx.x; i < n4; i += gridDim.x * blockDim.x) {
    int c4 = i & 31;
    float4 v = h[i];
    float4 sc = ((const float4*)scale)[c4];
    float4 sh = ((const float4*)shift)[c4];
    float4 r;
    r.x = tanhf(fmaf(v.x, sc.x, sh.x));
    r.y = tanhf(fmaf(v.y, sc.y, sh.y));
    r.z = tanhf(fmaf(v.z, sc.z, sh.z));
    r.w = tanhf(fmaf(v.w, sc.w, sh.w));
    o[i] = r;
  }
}

// ---------------- graph ranges + attention pool + final ----------------
__global__ void ranges_k(const int* __restrict__ batch, int* __restrict__ gstart, int* __restrict__ gend) {
  int i = blockIdx.x * 256 + threadIdx.x;
  if (i < NN) {
    int b = batch[i];
    atomicMin(&gstart[b], i);
    atomicMax(&gend[b], i + 1);
  }
}

__global__ void pool_k(const float* __restrict__ gate, const float* __restrict__ xin,
                       const int* __restrict__ gstart, const int* __restrict__ gend,
                       float* __restrict__ pooled) {
  const int g = blockIdx.x, j = threadIdx.x;
  const int st = gstart[g];
  if (st == 0x7f7f7f7f) { pooled[(size_t)g * HD + j] = 0.f; return; }
  const int en = gend[g];
  float m = -INFINITY, s = 0.f, p = 0.f;
  for (int n = st; n < en; ++n) {
    const float gv = gate[(size_t)n * HD + j];
    const float hv = xin[(size_t)n * HD + j];
    const float nm = fmaxf(m, gv);
    const float c = __expf(m - nm);
    const float w = __expf(gv - nm);
    s = s * c + w;
    p = p * c + w * hv;
    m = nm;
  }
  pooled[(size_t)g * HD + j] = p / fmaxf(s, 1e-16f);
}

__global__ void final_k(const float* __restrict__ pooled, const float* __restrict__ Wf,
                        const float* __restrict__ bf, float* __restrict__ out) {
  __shared__ float ps[HD];
  const int g = blockIdx.x, j = threadIdx.x;
  ps[j] = pooled[(size_t)g * HD + j];
  __syncthreads();
  float acc = bf[j];
#pragma unroll 8
  for (int i = 0; i < HD; ++i) acc = fmaf(ps[i], Wf[i * HD + j], acc);
  out[(size_t)g * HD + j] = tanhf(acc) * PI_F;                   // axis
  out[(size_t)(NG + g) * HD + j] = 0.f;                          // aperture
}

extern "C" void kernel_launch(void* const* d_in, const int* in_sizes, int n_in,
                              void* d_out, int out_size, void* d_ws, size_t ws_size,
                              hipStream_t stream) {
  const float* x     = (const float*)d_in[0];
  const int*   eidx  = (const int*)d_in[1];
  const float* eattr = (const float*)d_in[2];
  const int*   batch = (const int*)d_in[3];
  const float *Wl1 = (const float*)d_in[4],  *bl1 = (const float*)d_in[5];
  const float *Wr1 = (const float*)d_in[6],  *br1 = (const float*)d_in[7];
  const float *We1 = (const float*)d_in[8],  *att1 = (const float*)d_in[9],  *cb1 = (const float*)d_in[10];
  const float *Wl2 = (const float*)d_in[11], *bl2 = (const float*)d_in[12];
  const float *Wr2 = (const float*)d_in[13], *br2 = (const float*)d_in[14];
  const float *We2 = (const float*)d_in[15], *att2 = (const float*)d_in[16], *cb2 = (const float*)d_in[17];
  const float *g1 = (const float*)d_in[18],  *be1 = (const float*)d_in[19];
  const float *g2 = (const float*)d_in[20],  *be2 = (const float*)d_in[21];
  const float *A1 = (const float*)d_in[22],  *a1 = (const float*)d_in[23];
  const float *A2 = (const float*)d_in[24],  *a2 = (const float*)d_in[25];
  const float *Wf = (const float*)d_in[26],  *bf = (const float*)d_in[27];
  const int* src = eidx;
  const int* dst = eidx + NE;

  float* ws = (float*)d_ws;
  const size_t NH = (size_t)NN * HD;
  float* sloopb = ws;
  float* xl     = ws + NH;
  float* xr     = ws + 2 * NH;
  float* hbuf   = ws + 3 * NH;
  float* hpr    = ws + 4 * NH;
  float* ev     = ws + 5 * NH;                 // NE+NN floats
  float* cs     = ev + (NE + NN);
  float* csq    = cs + HD;
  float* scale  = csq + HD;
  float* shift  = scale + HD;
  float* pooled = shift + HD;                  // NG*HD
  int* ideg     = (int*)(pooled + (size_t)NG * HD);
  int* rowstart = ideg + NN;
  int* cursor   = rowstart + NN;
  int* ceid     = cursor + NN;
  int* csrc     = ceid + NE;
  int* gstart   = csrc + NE;
  int* gend     = gstart + NG;
  int* part     = gend + NG;                   // 64 ints

  const int nbScan = (NN + 1023) / 1024;       // 49
  const int nbE = (NE + 255) / 256;            // 2344
  const int nbN = (NN + 255) / 256;            // 196

  // ---- CSR build (reused by both layers) ----
  hipMemsetAsync(ideg, 0, NN * sizeof(int), stream);
  hipMemsetAsync(gstart, 0x7f, NG * sizeof(int), stream);
  hipMemsetAsync(gend, 0, NG * sizeof(int), stream);
  deg_hist<<<nbE, 256, 0, stream>>>(dst, ideg);
  scanA<<<nbScan, 256, 0, stream>>>(ideg, part);
  scanB<<<1, 64, 0, stream>>>(part, nbScan);
  scanC<<<nbScan, 256, 0, stream>>>(ideg, part, rowstart, cursor);
  scatter_k<<<nbE, 256, 0, stream>>>(src, dst, cursor, ceid, csrc);
  sloop_k<<<NN / 2, 256, 0, stream>>>(eattr, rowstart, ideg, ceid, sloopb);

  // ---- layer 1 ----
  node_gemm<1, 0><<<(NN + 31) / 32, 256, 0, stream>>>(x, Wl1, bl1, Wr1, br1, xl, xr);
  edge_scores<<<512, 256, 0, stream>>>(eattr, sloopb, src, dst, xl, xr, We1, att1, ev);
  aggregate<<<NN / 2, 256, 0, stream>>>(xl, ev, rowstart, ideg, ceid, csrc, cb1, hbuf);
  hipMemsetAsync(cs, 0, 2 * HD * sizeof(float), stream);
  colstats<<<nbN, 256, 0, stream>>>(hbuf, cs, csq);
  bnfinal<<<1, 128, 0, stream>>>(cs, csq, g1, be1, scale, shift);
  bn_tanh<<<1024, 256, 0, stream>>>((const float4*)hbuf, scale, shift, (float4*)hpr);

  // ---- layer 2 ----
  node_gemm<1, 0><<<(NN + 31) / 32, 256, 0, stream>>>(hpr, Wl2, bl2, Wr2, br2, xl, xr);
  edge_scores<<<512, 256, 0, stream>>>(eattr, sloopb, src, dst, xl, xr, We2, att2, ev);
  aggregate<<<NN / 2, 256, 0, stream>>>(xl, ev, rowstart, ideg, ceid, csrc, cb2, hbuf);
  hipMemsetAsync(cs, 0, 2 * HD * sizeof(float), stream);
  colstats<<<nbN, 256, 0, stream>>>(hbuf, cs, csq);
  bnfinal<<<1, 128, 0, stream>>>(cs, csq, g2, be2, scale, shift);
  bn_tanh<<<1024, 256, 0, stream>>>((const float4*)hbuf, scale, shift, (float4*)hpr);

  // ---- attention pooling + final linear ----
  node_gemm<0, 1><<<(NN + 31) / 32, 256, 0, stream>>>(hpr, A1, a1, nullptr, nullptr, xr, nullptr);
  node_gemm<0, 0><<<(NN + 31) / 32, 256, 0, stream>>>(xr, A2, a2, nullptr, nullptr, xl, nullptr);
  ranges_k<<<nbN, 256, 0, stream>>>(batch, gstart, gend);
  pool_k<<<NG, 128, 0, stream>>>(xl, hpr, gstart, gend, pooled);
  final_k<<<NG, 128, 0, stream>>>(pooled, Wf, bf, (float*)d_out);
}